// Round 10
// baseline (160.711 us; speedup 1.0000x reference)
//
#include <hip/hip_runtime.h>
#include <hip/hip_bf16.h>
#include <stdint.h>

// out[i][j] = dot(x[i], y[j]) / max(|x[i]|*|y[j]|, 1e-8) / 0.05
// x,y: [4096,1024] f32; out: [4096,4096] f32
// SINGLE fused kernel: f32 -> bf16 conversion happens during staging (prep
// kernel, Xb/Yb workspace, and rnx/rny arrays eliminated); row norms are
// accumulated in f32 during staging and reduced into LDS at the end.
#define MDIM 4096
#define NDIM 4096
#define KDIM 1024
#define TEMP_INV 20.0f

#define BM 128
#define BN 128
#define BK 64
#define NT (KDIM / BK)       // 16 K-tiles
#define ABUF_E (BM * BK)     // 8192 elems = 16 KB (A region; B same)
#define BUF_E (2 * ABUF_E)   // 32 KB per buffer; 2 buffers = 64 KB -> 2 blocks/CU

typedef __bf16 bf16x8 __attribute__((ext_vector_type(8)));
typedef float f32x4 __attribute__((ext_vector_type(4)));

// RNE f32->bf16 (verified in prep across all passing rounds), packed pair.
__device__ __forceinline__ uint32_t pkbf(uint32_t u0, uint32_t u1) {
    uint32_t lo = (u0 + 0x7FFFu + ((u0 >> 16) & 1u)) >> 16;
    uint32_t hi = (u1 + 0x7FFFu + ((u1 >> 16) & 1u)) & 0xFFFF0000u;
    return lo | hi;
}

// 8 f32 -> 16 B packed bf16 into LDS + sum-of-squares accumulate.
__device__ __forceinline__ void cvt_store(const float4 v0, const float4 v1,
                                          __bf16* dst, float& ss) {
    ss += v0.x * v0.x + v0.y * v0.y + v0.z * v0.z + v0.w * v0.w +
          v1.x * v1.x + v1.y * v1.y + v1.z * v1.z + v1.w * v1.w;
    union { float4 f; uint32_t u[4]; } a, b;
    a.f = v0; b.f = v1;
    uint4 w;
    w.x = pkbf(a.u[0], a.u[1]);
    w.y = pkbf(a.u[2], a.u[3]);
    w.z = pkbf(b.u[0], b.u[1]);
    w.w = pkbf(b.u[2], b.u[3]);
    *(uint4*)dst = w;
}

// One K-tile (BK=64, 128x128 tile, 4 waves, wave tile 64x64, 16x16x32 MFMA).
// STAGE: (1) issue 16 f32 global loads for tile t+1 at top (latency hidden
// under this tile's ds_reads+MFMA), (2) after MFMA, convert->bf16, accumulate
// row sum-of-squares, ds_write_b128 to the other buffer at the EXACT linear
// addresses the verified DMA path used (thread t -> elem t*8 of seg j; global
// chunk pre-swizzled: gch = (t&7)^(srow&7)), (3) one __syncthreads.
template <bool STAGE>
__device__ __forceinline__ void ktile(const __bf16* __restrict__ buf,
                                      __bf16* __restrict__ nbuf,
                                      const float* gAf, const float* gBf, int ktn,
                                      int aRow, int bRow, int cp0, int cp1,
                                      int tid, f32x4 (&acc)[4][4],
                                      float (&ssA)[4], float (&ssB)[4]) {
    float4 av[4][2], bv[4][2];
    if constexpr (STAGE) {
#pragma unroll
        for (int j = 0; j < 4; ++j) {
            const float4* pa = (const float4*)(gAf + ktn + (size_t)(j * 32) * KDIM);
            const float4* pb = (const float4*)(gBf + ktn + (size_t)(j * 32) * KDIM);
            av[j][0] = pa[0]; av[j][1] = pa[1];
            bv[j][0] = pb[0]; bv[j][1] = pb[1];
        }
    }

    bf16x8 aF[4][2], bF[4][2];
#pragma unroll
    for (int mi = 0; mi < 4; ++mi) {
        aF[mi][0] = *(const bf16x8*)(buf + aRow + mi * 1024 + cp0);
        aF[mi][1] = *(const bf16x8*)(buf + aRow + mi * 1024 + cp1);
    }
#pragma unroll
    for (int ni = 0; ni < 4; ++ni) {
        bF[ni][0] = *(const bf16x8*)(buf + bRow + ni * 1024 + cp0);
        bF[ni][1] = *(const bf16x8*)(buf + bRow + ni * 1024 + cp1);
    }

    __builtin_amdgcn_s_setprio(1);
#pragma unroll
    for (int kh = 0; kh < 2; ++kh)
#pragma unroll
        for (int ni = 0; ni < 4; ++ni)
#pragma unroll
            for (int mi = 0; mi < 4; ++mi)
                acc[mi][ni] = __builtin_amdgcn_mfma_f32_16x16x32_bf16(
                    aF[mi][kh], bF[ni][kh], acc[mi][ni], 0, 0, 0);
    __builtin_amdgcn_s_setprio(0);

    if constexpr (STAGE) {
#pragma unroll
        for (int j = 0; j < 4; ++j) {
            cvt_store(av[j][0], av[j][1], nbuf + j * 2048 + tid * 8, ssA[j]);
            cvt_store(bv[j][0], bv[j][1], nbuf + ABUF_E + j * 2048 + tid * 8, ssB[j]);
        }
    }
    __syncthreads();
}

// 128x128 tile, BK=64, 256 threads / 4 waves (2M x 2N), wave tile 64x64,
// 16x16x32 MFMA, 2 LDS buffers (64 KB) -> 2 resident blocks/CU, 4 queued/CU.
// Staging reads f32 x/y directly; norms computed in-kernel (f32, exact same
// math as the old prep kernel) and served from LDS in the epilogue.
__global__ __launch_bounds__(256, 2) void gemm_cos_kernel(const float* __restrict__ x,
                                                          const float* __restrict__ y,
                                                          float* __restrict__ out) {
    __shared__ __bf16 lds[2 * BUF_E];  // 64 KB
    __shared__ float rnxs[BM], rnys[BN];

    const int tid = threadIdx.x;

    // Rect XCD swizzle: 1024 blocks = 8 XCD x 128; each XCD gets an 8bm x 16bn
    // rectangle (verified bijective, R8/R9).
    const int lin = (int)(blockIdx.y * gridDim.x + blockIdx.x);
    const int x8 = lin & 7;
    const int ii = lin >> 3;  // 0..127 within XCD
    const int bm = (x8 >> 1) * 8 + (ii >> 4);
    const int bn = (x8 & 1) * 16 + (ii & 15);

    // Staging map (identical to the verified DMA layout): thread t covers
    // seg-rows {srow, srow+32, srow+64, srow+96}, chunk slot (t&7); fetches
    // global chunk gch = (t&7)^(srow&7) so LDS slot c' holds chunk c'^(row&7).
    const int srow = tid >> 3;
    const int gch = (tid & 7) ^ (srow & 7);
    const float* gAf = x + (size_t)(bm * BM + srow) * KDIM + gch * 8;
    const float* gBf = y + (size_t)(bn * BN + srow) * KDIM + gch * 8;

    const int lane = tid & 63;
    const int wv = tid >> 6;
    const int wm = wv >> 1;   // 0..1 -> A rows wm*64..
    const int wn = wv & 1;    // 0..1 -> B rows wn*64..
    const int l15 = lane & 15;
    const int kb = lane >> 4;      // 0..3 k-block
    const int sw = lane & 7;       // swizzle xor term (row&7 of the frag row)

    const int aRow = (wm * 64 + l15) * 64;             // + mi*1024 + cp
    const int bRow = ABUF_E + (wn * 64 + l15) * 64;    // + ni*1024 + cp
    const int cp0 = (kb ^ sw) * 8;                     // kh=0 chunk
    const int cp1 = ((4 + kb) ^ sw) * 8;               // kh=1 chunk

    f32x4 acc[4][4];
#pragma unroll
    for (int i = 0; i < 4; ++i)
#pragma unroll
        for (int j = 0; j < 4; ++j) acc[i][j] = (f32x4){};

    float ssA[4] = {0.f, 0.f, 0.f, 0.f};
    float ssB[4] = {0.f, 0.f, 0.f, 0.f};

    __bf16* buf0 = lds;
    __bf16* buf1 = lds + BUF_E;

    // ---- prologue: stage tile 0 -> buf0 (loads + cvt + ss + write)
    {
#pragma unroll
        for (int j = 0; j < 4; ++j) {
            const float4* pa = (const float4*)(gAf + (size_t)(j * 32) * KDIM);
            const float4* pb = (const float4*)(gBf + (size_t)(j * 32) * KDIM);
            float4 a0 = pa[0], a1 = pa[1], b0 = pb[0], b1 = pb[1];
            cvt_store(a0, a1, buf0 + j * 2048 + tid * 8, ssA[j]);
            cvt_store(b0, b1, buf0 + ABUF_E + j * 2048 + tid * 8, ssB[j]);
        }
    }
    __syncthreads();

    // ---- main loop: ping-pong pairs, staging t+1 during t
#pragma unroll 1
    for (int t = 0; t < NT - 2; t += 2) {
        ktile<true>(buf0, buf1, gAf, gBf, (t + 1) * BK, aRow, bRow, cp0, cp1, tid,
                    acc, ssA, ssB);
        ktile<true>(buf1, buf0, gAf, gBf, (t + 2) * BK, aRow, bRow, cp0, cp1, tid,
                    acc, ssA, ssB);
    }
    // tile 14 (buf0): stage tile 15 -> buf1
    ktile<true>(buf0, buf1, gAf, gBf, 15 * BK, aRow, bRow, cp0, cp1, tid,
                acc, ssA, ssB);
    // tile 15 (buf1): no staging
    ktile<false>(buf1, buf0, gAf, gBf, 0, aRow, bRow, cp0, cp1, tid, acc, ssA, ssB);

    // ---- norms: ssA[j]/ssB[j] is this thread's chunk-partial for panel row
    // (srow + j*32); the row's 8 chunk-slots are the 8 adjacent lanes.
#pragma unroll
    for (int j = 0; j < 4; ++j) {
        float sa = ssA[j];
        sa += __shfl_xor(sa, 1); sa += __shfl_xor(sa, 2); sa += __shfl_xor(sa, 4);
        float sb = ssB[j];
        sb += __shfl_xor(sb, 1); sb += __shfl_xor(sb, 2); sb += __shfl_xor(sb, 4);
        if ((tid & 7) == 0) {
            rnxs[srow + j * 32] = 1.0f / fmaxf(sqrtf(sa), 1e-8f);
            rnys[srow + j * 32] = 1.0f / fmaxf(sqrtf(sb), 1e-8f);
        }
    }
    __syncthreads();

    // Epilogue. C/D (16x16, m89/m91): col = lane&15, row = (lane>>4)*4 + reg.
    const int prbase = wm * 64 + kb * 4;       // panel row base
    const int pcbase = wn * 64 + l15;          // panel col base
    const int grbase = bm * BM + prbase;
    const int gcbase = bn * BN + pcbase;
    float sy[4];
#pragma unroll
    for (int ni = 0; ni < 4; ++ni) sy[ni] = rnys[pcbase + ni * 16] * TEMP_INV;

#pragma unroll
    for (int mi = 0; mi < 4; ++mi) {
#pragma unroll
        for (int r = 0; r < 4; ++r) {
            const int grow = grbase + mi * 16 + r;
            const float rx = rnxs[prbase + mi * 16 + r];
            float* orow = out + (size_t)grow * NDIM;
#pragma unroll
            for (int ni = 0; ni < 4; ++ni)
                orow[gcbase + ni * 16] = acc[mi][ni][r] * rx * sy[ni];
        }
    }
}

extern "C" void kernel_launch(void* const* d_in, const int* in_sizes, int n_in,
                              void* d_out, int out_size, void* d_ws, size_t ws_size,
                              hipStream_t stream) {
    const float* x = (const float*)d_in[0];
    const float* y = (const float*)d_in[1];
    float* out = (float*)d_out;
    (void)d_ws; (void)ws_size;

    gemm_cos_kernel<<<dim3(NDIM / BN, MDIM / BM), 256, 0, stream>>>(x, y, out);
}